// Round 6
// baseline (958.886 us; speedup 1.0000x reference)
//
#include <hip/hip_runtime.h>
#include <math.h>

#pragma clang fp contract(off)

#define MPTS   2097152
#define NIMG   16
#define NCLS   11
#define NBINS  5120
#define BASEB  0x3D000000u
#define CAP    4096
#define SORTN  4096
#define TOPN   1000
#define OUTN   100

// exact f32 sigmoid mirroring numpy: e = f32(exp64(-x)) [CR expf]; 1/(1+e) in f32
__device__ inline float sigx(float x) {
    float e = (float)exp(-(double)x);
    return 1.0f / (1.0f + e);
}
// fast screen-only sigmoid (~2e-7 rel err)
__device__ inline float sigf(float x) {
    float e = __expf(-x);
    return 1.0f / (1.0f + e);
}
// round f32 -> bf16 (RNE) -> f32, to match the bf16-quantized reference
__device__ inline float bfr(float x) {
    unsigned u = __float_as_uint(x);
    unsigned r = (u + 0x7FFFu + ((u >> 16) & 1u)) & 0xFFFF0000u;
    return __uint_as_float(r);
}

// ---- pass A: per-image histogram of f32 score bits ---------------------
__global__ void k_hist(const float* __restrict__ cls, const float* __restrict__ ctr,
                       const int* __restrict__ batch, unsigned* __restrict__ ghist) {
    __shared__ unsigned hist[NBINS];
    __shared__ int simg;
    const int PPB = MPTS / 512;
    int p0 = blockIdx.x * PPB;
    for (int i = threadIdx.x; i < NBINS; i += 256) hist[i] = 0;
    if (threadIdx.x == 0) simg = batch[p0];
    __syncthreads();
    int bi = simg;
    for (int p = p0 + threadIdx.x; p < p0 + PPB; p += 256) {
        int b = batch[p];
        float c32 = ctr[p];
        float sfc = sigf(c32);
        float sxc = 0.0f; bool havex = false;
        const float* cp = cls + (size_t)p * NCLS;
        #pragma unroll
        for (int k = 0; k < 10; k++) {               // class 10 zeroed by ref
            float ck = cp[k];
            float sf = sigf(ck) * sfc;
            if (sf > 0.0497f) {                      // screen (margin >> 5e-6 rel err)
                if (!havex) { sxc = sigx(c32); havex = true; }
                float s = sigx(ck) * sxc;            // exact f32 chain
                if (s > 0.05f) {
                    unsigned bin = (__float_as_uint(s) - BASEB) >> 13;
                    if (b == bi) atomicAdd(&hist[bin], 1u);
                    else         atomicAdd(&ghist[(size_t)b * NBINS + bin], 1u);
                }
            }
        }
    }
    __syncthreads();
    unsigned* gh = ghist + (size_t)bi * NBINS;
    for (int i = threadIdx.x; i < NBINS; i += 256) {
        unsigned v = hist[i];
        if (v) atomicAdd(&gh[i], v);
    }
}

// ---- threshold: largest bin B with suffix-count >= TOPN ----------------
__global__ void k_thresh(const unsigned* __restrict__ ghist, unsigned* __restrict__ thrbuf) {
    int img = blockIdx.x;
    const unsigned* h = ghist + (size_t)img * NBINS;
    __shared__ unsigned psum[256];
    int t = threadIdx.x;
    unsigned s = 0;
    for (int i = 0; i < 20; i++) s += h[t * 20 + i];
    psum[t] = s;
    __syncthreads();
    if (t == 0) {
        unsigned run = 0; int B = 0;
        for (int u = 255; u >= 0; u--) {
            if (run + psum[u] >= (unsigned)TOPN) {
                for (int b = u * 20 + 19; b >= u * 20; b--) {
                    run += h[b];
                    if (run >= (unsigned)TOPN) { B = b; break; }
                }
                break;
            }
            run += psum[u];
        }
        unsigned TB = BASEB + ((unsigned)B << 13);
        thrbuf[2 * img] = TB;
        thrbuf[2 * img + 1] = __float_as_uint(__uint_as_float(TB) * 0.998f); // screen
    }
}

// ---- pass B: collect u64 keys (f32 bits desc, idx asc) -----------------
__global__ void k_collect(const float* __restrict__ cls, const float* __restrict__ ctr,
                          const int* __restrict__ batch, const unsigned* __restrict__ thrbuf,
                          unsigned* __restrict__ cnt, unsigned long long* __restrict__ cand) {
    __shared__ unsigned sTB[NIMG];
    __shared__ float sSCR[NIMG];
    if (threadIdx.x < NIMG) {
        sTB[threadIdx.x]  = thrbuf[2 * threadIdx.x];
        sSCR[threadIdx.x] = __uint_as_float(thrbuf[2 * threadIdx.x + 1]);
    }
    __syncthreads();
    const int PPB = MPTS / 512;
    int p0 = blockIdx.x * PPB;
    for (int p = p0 + threadIdx.x; p < p0 + PPB; p += 256) {
        int b = batch[p];
        unsigned TB = sTB[b];
        float scr = sSCR[b];
        float c32 = ctr[p];
        float sfc = sigf(c32);
        float sxc = 0.0f; bool havex = false;
        const float* cp = cls + (size_t)p * NCLS;
        #pragma unroll
        for (int k = 0; k < 10; k++) {
            float ck = cp[k];
            float sf = sigf(ck) * sfc;
            if (sf > scr) {
                if (!havex) { sxc = sigx(c32); havex = true; }
                float s = sigx(ck) * sxc;
                unsigned bits = __float_as_uint(s);
                if (bits >= TB && s > 0.05f) {
                    unsigned pos = atomicAdd(&cnt[b], 1u);
                    if (pos < CAP) {
                        unsigned idx = (unsigned)(p * NCLS + k);
                        cand[(size_t)b * CAP + pos] =
                            ((unsigned long long)bits << 32) | (unsigned long long)(0xFFFFFFFFu - idx);
                    }
                }
            }
        }
    }
}

// ---- exact sort + f32 box build (bit-exact np f32 op order) ------------
__global__ void k_build(const unsigned long long* __restrict__ cand, const unsigned* __restrict__ cnt,
                        const float* __restrict__ loc, const float* __restrict__ breg,
                        const int* __restrict__ levels, const int* __restrict__ imsz,
                        float* __restrict__ bx, float* __restrict__ sc, int* __restrict__ cl,
                        unsigned* __restrict__ k0, float* __restrict__ bo, float* __restrict__ ar) {
    int img = blockIdx.x;
    __shared__ unsigned long long skey[SORTN];
    __shared__ float red[256];
    __shared__ float smc;
    unsigned n = cnt[img]; if (n > SORTN) n = SORTN;
    for (int i = threadIdx.x; i < SORTN; i += 256)
        skey[i] = (i < (int)n) ? cand[(size_t)img * CAP + i] : 0ull;
    __syncthreads();
    for (unsigned kk = 2; kk <= SORTN; kk <<= 1) {
        for (unsigned j = kk >> 1; j > 0; j >>= 1) {
            for (unsigned i = threadIdx.x; i < SORTN; i += 256) {
                unsigned ixj = i ^ j;
                if (ixj > i) {
                    unsigned long long a = skey[i], b = skey[ixj];
                    bool up = ((i & kk) == 0);
                    bool sw = up ? (a < b) : (a > b);   // descending (keys unique)
                    if (sw) { skey[i] = b; skey[ixj] = a; }
                }
            }
            __syncthreads();
        }
    }
    float wmax = (float)imsz[img * 2 + 1] - 1.0f;   // hw = [h, w] -> w-1
    float hmax = (float)imsz[img * 2 + 0] - 1.0f;
    float lmax = 0.0f;
    for (int r = threadIdx.x; r < TOPN; r += 256) {
        unsigned long long kv = skey[r];
        unsigned bits = (unsigned)(kv >> 32);
        unsigned idx = 0xFFFFFFFFu - (unsigned)(kv & 0xFFFFFFFFull);
        float v = __uint_as_float(bits);
        bool v0 = (kv != 0ull) && (v > 0.0f);
        if (!v0) idx = 0;
        unsigned pt = idx / NCLS;
        int c = (int)(idx - pt * NCLS);
        float lx = loc[(size_t)pt * 2 + 0], ly = loc[(size_t)pt * 2 + 1];
        float st = (float)(8 << levels[pt]);        // 8..128, pow2 -> exact scaling
        float r0 = breg[(size_t)pt * 4 + 0] * st;
        float r1 = breg[(size_t)pt * 4 + 1] * st;
        float r2 = breg[(size_t)pt * 4 + 2] * st;
        float r3 = breg[(size_t)pt * 4 + 3] * st;
        float x1 = lx - r0, y1 = ly - r1, x2 = lx + r2, y2 = ly + r3;
        x1 = fminf(fmaxf(x1, 0.0f), wmax);
        y1 = fminf(fmaxf(y1, 0.0f), hmax);
        x2 = fminf(fmaxf(x2, 0.0f), wmax);
        y2 = fminf(fmaxf(y2, 0.0f), hmax);
        float wss = (x2 - x1) + 1.0f, hss = (y2 - y1) + 1.0f;
        bool keep = v0 && (wss >= 0.0f) && (hss >= 0.0f);
        size_t ob = (size_t)img * TOPN + r;
        bx[ob * 4 + 0] = x1; bx[ob * 4 + 1] = y1;
        bx[ob * 4 + 2] = x2; bx[ob * 4 + 3] = y2;
        sc[ob] = v0 ? sqrtf(v) : 0.0f;
        cl[ob] = c + 1;
        k0[ob] = keep ? 1u : 0u;
        if (keep) lmax = fmaxf(lmax, fmaxf(fmaxf(x1, y1), fmaxf(x2, y2)));
    }
    red[threadIdx.x] = lmax; __syncthreads();
    for (int sft = 128; sft > 0; sft >>= 1) {
        if (threadIdx.x < sft) red[threadIdx.x] = fmaxf(red[threadIdx.x], red[threadIdx.x + sft]);
        __syncthreads();
    }
    if (threadIdx.x == 0) smc = red[0];
    __syncthreads();
    float off1 = smc + 1.0f;                        // max_coord + 1.0 (f32)
    for (int r = threadIdx.x; r < TOPN; r += 256) {
        size_t ob = (size_t)img * TOPN + r;
        float o = (float)cl[ob] * off1;             // cl.astype(f32) * (mc+1)
        float x1 = bx[ob * 4 + 0] + o, y1 = bx[ob * 4 + 1] + o;
        float x2 = bx[ob * 4 + 2] + o, y2 = bx[ob * 4 + 3] + o;
        bo[ob * 4 + 0] = x1; bo[ob * 4 + 1] = y1;
        bo[ob * 4 + 2] = x2; bo[ob * 4 + 3] = y2;
        float aw = fmaxf((x2 - x1) + 1.0f, 0.0f);   // clip(x2-x1+1, 0)
        float ah = fmaxf((y2 - y1) + 1.0f, 0.0f);
        ar[ob] = aw * ah;
    }
}

// ---- exact f32 greedy NMS + top-100 output (1 block/image) -------------
__global__ __launch_bounds__(1024)
void k_nms_out(const float* __restrict__ bo, const float* __restrict__ ar,
               const unsigned* __restrict__ k0, const float* __restrict__ bx,
               const float* __restrict__ sc, const int* __restrict__ cl,
               float* __restrict__ out) {
    int img = blockIdx.x;
    __shared__ float sx1[TOPN], sy1[TOPN], sx2[TOPN], sy2[TOPN], sar[TOPN];
    __shared__ unsigned char kp[TOPN];
    __shared__ int fi[OUTN];
    __shared__ int snk;
    int t = threadIdx.x;
    for (int i = t; i < TOPN; i += 1024) {
        size_t ob = (size_t)img * TOPN + i;
        sx1[i] = bo[ob * 4 + 0]; sy1[i] = bo[ob * 4 + 1];
        sx2[i] = bo[ob * 4 + 2]; sy2[i] = bo[ob * 4 + 3];
        sar[i] = ar[ob];
        kp[i]  = (unsigned char)k0[ob];
    }
    __syncthreads();
    float bx1 = 0, by1 = 0, bx2 = 0, by2 = 0, bar = 0;
    if (t < TOPN) { bx1 = sx1[t]; by1 = sy1[t]; bx2 = sx2[t]; by2 = sy2[t]; bar = sar[t]; }
    for (int i = 0; i < TOPN; i++) {
        if (!kp[i]) continue;                       // uniform; iters that write end in barrier
        if (t < TOPN && t > i && kp[t]) {
            float xx1 = fmaxf(sx1[i], bx1);
            float yy1 = fmaxf(sy1[i], by1);
            float xx2 = fminf(sx2[i], bx2);
            float yy2 = fminf(sy2[i], by2);
            float iw = fmaxf((xx2 - xx1) + 1.0f, 0.0f);
            float ih = fmaxf((yy2 - yy1) + 1.0f, 0.0f);
            float inter = iw * ih;
            float den = fmaxf((sar[i] + bar) - inter, 1e-9f); // ref assoc order
            if (inter / den > 0.6f) kp[t] = 0;
        }
        __syncthreads();
    }
    if (t == 0) {
        int nf = 0;
        for (int r = 0; r < TOPN && nf < OUTN; r++) if (kp[r])  fi[nf++] = r;
        int nk = nf;
        for (int r = 0; r < TOPN && nf < OUTN; r++) if (!kp[r]) fi[nf++] = r;  // stable fill
        snk = nk;
    }
    __syncthreads();
    if (t < OUTN) {
        int r = fi[t];
        bool kv = t < snk;
        size_t ob = (size_t)img * TOPN + r;
        float sv = kv ? sc[ob] : 0.0f;
        int o = img * OUTN + t;
        out[o * 4 + 0] = bfr(bx[ob * 4 + 0]);
        out[o * 4 + 1] = bfr(bx[ob * 4 + 1]);
        out[o * 4 + 2] = bfr(bx[ob * 4 + 2]);
        out[o * 4 + 3] = bfr(bx[ob * 4 + 3]);
        out[6400 + o] = bfr(sv);
        out[8000 + o] = (float)cl[ob];
        out[9600 + o] = (sv > 0.0f) ? 1.0f : 0.0f;
    }
}

extern "C" void kernel_launch(void* const* d_in, const int* in_sizes, int n_in,
                              void* d_out, int out_size, void* d_ws, size_t ws_size,
                              hipStream_t stream) {
    const float* loc    = (const float*)d_in[0];
    const int*   levels = (const int*)d_in[1];
    const int*   batch  = (const int*)d_in[2];
    const float* cls    = (const float*)d_in[3];
    const float* breg   = (const float*)d_in[4];
    const float* ctr    = (const float*)d_in[5];
    const int*   imsz   = (const int*)d_in[6];

    char* ws = (char*)d_ws;
    unsigned long long* cand   = (unsigned long long*)(ws + 0);        // 16*4096*8 = 524288
    unsigned*           ghist  = (unsigned*)(ws + 524288);             // 16*5120*4 = 327680
    float*              bx     = (float*)(ws + 852032);                // pad to 64: 852032? keep 8-align
    // recompute offsets cleanly below
    bx    = (float*)(ws + 852096);                                     // 256000
    float*              bo     = (float*)(ws + 1108096);               // 256000
    float*              ar     = (float*)(ws + 1364096);               // 64000
    float*              sc     = (float*)(ws + 1428096);               // 64000
    int*                cl     = (int*)(ws + 1492096);                 // 64000
    unsigned*           k0     = (unsigned*)(ws + 1556096);            // 64000
    unsigned*           cnt    = (unsigned*)(ws + 1620096);            // 64
    unsigned*           thrbuf = (unsigned*)(ws + 1620160);            // 128
    float* out = (float*)d_out;

    hipMemsetAsync(ghist, 0, 16 * NBINS * 4, stream);
    hipMemsetAsync(cnt, 0, 64, stream);
    k_hist   <<<512, 256, 0, stream>>>(cls, ctr, batch, ghist);
    k_thresh <<<16,  256, 0, stream>>>(ghist, thrbuf);
    k_collect<<<512, 256, 0, stream>>>(cls, ctr, batch, thrbuf, cnt, cand);
    k_build  <<<16,  256, 0, stream>>>(cand, cnt, loc, breg, levels, imsz,
                                       bx, sc, cl, k0, bo, ar);
    k_nms_out<<<16, 1024, 0, stream>>>(bo, ar, k0, bx, sc, cl, out);
}